// Round 15
// baseline (97.702 us; speedup 1.0000x reference)
//
#include <hip/hip_runtime.h>

// BERT-CRF NER, two kernels.
//  K1 feats: byte-identical to round 14 (F ~= 39us, near L3-warm floor).
//  K2 viterbi: phase 1 rewritten — readlane/SGPR broadcast replaced by a
//     pure-VALU DPP row_ror ring: z rotates through the 16-lane row, each
//     lane accumulates m = max(m, trp[f] + z). trp[] is trans pre-permuted
//     per lane via the SAME hw rotation applied to an index vector (so the
//     rotation direction is irrelevant). Pads (lanes 13-15) pinned to -1e30.
//     Max reassociation is exact -> ld bit-identical; phases 2-5 untouched.
// B=256, T=256, H=768, L=13, START=11.
// Outputs (float32): [0..255] max_p/T; [256..65791] path.

#define NEGV (-10000.0f)

#define DPP_ADD(v, ctrl, rmask)                                               \
  v += __int_as_float(__builtin_amdgcn_update_dpp(                            \
      0, __float_as_int(v), (ctrl), (rmask), 0xF, true));

#define DPP_REDUCE64(v)                                                       \
  DPP_ADD(v, 0x111, 0xF)  /* row_shr:1  */                                    \
  DPP_ADD(v, 0x112, 0xF)  /* row_shr:2  */                                    \
  DPP_ADD(v, 0x114, 0xF)  /* row_shr:4  */                                    \
  DPP_ADD(v, 0x118, 0xF)  /* row_shr:8  */                                    \
  DPP_ADD(v, 0x142, 0xA)  /* row_bcast:15 */                                  \
  DPP_ADD(v, 0x143, 0xC)  /* row_bcast:31 */

// ---------------------------------------------------------------- kernel 1 --
__global__ __launch_bounds__(256)
__attribute__((amdgpu_waves_per_eu(2, 2)))
void feats_kernel(
    const float* __restrict__ X,      // [65536, 768]
    const float* __restrict__ W,      // [13, 768]
    const float* __restrict__ bias,   // [13]
    float* __restrict__ featsT)       // [13][65536]
{
  const int tid = threadIdx.x;
  const int w = tid >> 6, l = tid & 63;
  const long row0 = (long)blockIdx.x * 128 + w * 32;

  float wreg[13][12];
  #pragma unroll
  for (int col = 0; col < 13; ++col) {
    #pragma unroll
    for (int j = 0; j < 3; ++j) {
      float4 v = *reinterpret_cast<const float4*>(W + col * 768 + 256 * j + 4 * l);
      wreg[col][4 * j + 0] = v.x; wreg[col][4 * j + 1] = v.y;
      wreg[col][4 * j + 2] = v.z; wreg[col][4 * j + 3] = v.w;
    }
  }
  float bs[13];
  #pragma unroll
  for (int c = 0; c < 13; ++c) bs[c] = bias[c];

  const float* xp = X + row0 * 768 + 4 * l;

  float4 buf[4][3];
  #pragma unroll
  for (int i = 0; i < 4; ++i) {
    buf[i][0] = *reinterpret_cast<const float4*>(xp + i * 768);
    buf[i][1] = *reinterpret_cast<const float4*>(xp + i * 768 + 256);
    buf[i][2] = *reinterpret_cast<const float4*>(xp + i * 768 + 512);
  }

  #pragma unroll 4
  for (int r = 0; r < 32; ++r) {
    const int s = r & 3;
    const float4 b0 = buf[s][0], b1 = buf[s][1], b2 = buf[s][2];

    float acc[13];
    #pragma unroll
    for (int c = 0; c < 13; ++c) acc[c] = 0.0f;
    #pragma unroll
    for (int col = 0; col < 13; ++col) {
      acc[col] = fmaf(b0.x, wreg[col][0],  acc[col]);
      acc[col] = fmaf(b0.y, wreg[col][1],  acc[col]);
      acc[col] = fmaf(b0.z, wreg[col][2],  acc[col]);
      acc[col] = fmaf(b0.w, wreg[col][3],  acc[col]);
      acc[col] = fmaf(b1.x, wreg[col][4],  acc[col]);
      acc[col] = fmaf(b1.y, wreg[col][5],  acc[col]);
      acc[col] = fmaf(b1.z, wreg[col][6],  acc[col]);
      acc[col] = fmaf(b1.w, wreg[col][7],  acc[col]);
      acc[col] = fmaf(b2.x, wreg[col][8],  acc[col]);
      acc[col] = fmaf(b2.y, wreg[col][9],  acc[col]);
      acc[col] = fmaf(b2.z, wreg[col][10], acc[col]);
      acc[col] = fmaf(b2.w, wreg[col][11], acc[col]);
    }

    #pragma unroll
    for (int c = 0; c < 13; ++c) {
      DPP_REDUCE64(acc[c])
    }

    if (l == 63) {
      #pragma unroll
      for (int c = 0; c < 13; ++c)
        featsT[(long)c * 65536 + row0 + r] = acc[c] + bs[c];
    }

    {
      const int pr = (r + 4 < 32) ? (r + 4) : 31;
      const float* xn = xp + pr * 768;
      buf[s][0] = *reinterpret_cast<const float4*>(xn);
      buf[s][1] = *reinterpret_cast<const float4*>(xn + 256);
      buf[s][2] = *reinterpret_cast<const float4*>(xn + 512);
    }
  }
}

// ---------------------------------------------------------------- kernel 2 --
__global__ __launch_bounds__(256) void viterbi_kernel(
    const float* __restrict__ featsT,  // [13][65536]
    const float* __restrict__ trans,   // [13,13]
    float* __restrict__ out)           // [256 + 65536]
{
  __shared__ float fsT[13 * 260];          // feats transposed [to][t] (pad 260)
  __shared__ float lds_ld[256 * 16];       // ld_t[to], t = 0..255
  __shared__ float trL[176];               // trans (169 used)
  __shared__ unsigned char psi[256 * 16];  // psi[t][to]
  __shared__ unsigned char Mm[256];        // [16 chunks][16]
  __shared__ unsigned char bnd[16];
  __shared__ unsigned char path[256];

  const int tid = threadIdx.x;
  const int w = tid >> 6, lane = tid & 63;
  const int b = blockIdx.x;

  #pragma unroll
  for (int i = 0; i < 13; ++i)
    fsT[i * 260 + tid] = featsT[(long)i * 65536 + b * 256 + tid];
  if (tid < 169) trL[tid] = trans[tid];
  __syncthreads();

  // ---- phase 1: serial forward (values only), DPP ring rotation ----
  if (w == 0 && lane < 16) {
    // trans pre-permuted per lane, tracked with the ACTUAL hw rotation:
    // after f rotations, this lane's z holds ld[idxf]; trp[f] = tr[lane][idxf].
    int idxf = lane;
    float trp[16];
    #pragma unroll
    for (int f = 0; f < 16; ++f) {
      trp[f] = (lane < 13 && idxf < 13) ? trL[lane * 13 + idxf] : 0.0f;
      if (f < 15)
        idxf = __builtin_amdgcn_update_dpp(0, idxf, 0x121, 0xF, 0xF, true);
    }

    const int toc = (lane < 13) ? lane : 0;
    const float* frow = &fsT[toc * 260];

    // pads (13-15) carry -1e30 so their rotated-in values never win the max
    float ld = (lane == 11) ? 0.0f : (lane < 13 ? NEGV : -1.0e30f);
    if (lane < 13) lds_ld[lane] = ld;       // t = 0

    float4 F[4], Fn[4];
    #pragma unroll
    for (int q = 0; q < 4; ++q)
      F[q] = *reinterpret_cast<const float4*>(frow + 4 * q);

    #pragma unroll 1
    for (int g = 0; g < 16; ++g) {
      if (g < 15) {
        #pragma unroll
        for (int q = 0; q < 4; ++q)
          Fn[q] = *reinterpret_cast<const float4*>(frow + (g + 1) * 16 + 4 * q);
      }
      const int kLo = (g == 0) ? 1 : 0;     // skip t = 0
      #pragma unroll
      for (int k = 0; k < 16; ++k) {
        if (k < kLo) continue;
        const int t = g * 16 + k;

        // m = max_f (trp[f] + rotate^f(ld)) — pure VALU, no SGPR hazards;
        // max reassociation is exact, so ld stays bit-identical.
        float z = ld;
        float m;
        #pragma unroll
        for (int f = 0; f < 16; ++f) {
          float c = trp[f] + z;
          m = (f == 0) ? c : fmaxf(m, c);
          if (f < 15)
            z = __int_as_float(__builtin_amdgcn_update_dpp(
                0, __float_as_int(z), 0x121, 0xF, 0xF, true));
        }

        const float4 fq = F[k >> 2];
        const float ft = ((k & 3) == 0) ? fq.x : ((k & 3) == 1) ? fq.y
                        : ((k & 3) == 2) ? fq.z : fq.w;
        ld = m + ft;
        ld = (lane < 13) ? ld : -1.0e30f;   // keep pads pinned
        if (lane < 13) lds_ld[t * 16 + lane] = ld;
      }
      #pragma unroll
      for (int q = 0; q < 4; ++q) F[q] = Fn[q];
    }
  }
  __syncthreads();

  // ---- phase 2: psi in parallel over t ----
  {
    const int to = tid & 15, dtt = tid >> 4;
    if (to < 13) {
      float trr[13];
      #pragma unroll
      for (int f = 0; f < 13; ++f) trr[f] = trL[to * 13 + f];
      for (int t = (dtt == 0 ? 16 : dtt); t < 256; t += 16) {
        const float* lp = &lds_ld[(t - 1) * 16];
        float4 l0 = *reinterpret_cast<const float4*>(lp);
        float4 l1 = *reinterpret_cast<const float4*>(lp + 4);
        float4 l2 = *reinterpret_cast<const float4*>(lp + 8);
        float4 l3 = *reinterpret_cast<const float4*>(lp + 12);
        float c[13] = {trr[0] + l0.x,  trr[1] + l0.y,  trr[2] + l0.z,
                       trr[3] + l0.w,  trr[4] + l1.x,  trr[5] + l1.y,
                       trr[6] + l1.z,  trr[7] + l1.w,  trr[8] + l2.x,
                       trr[9] + l2.y,  trr[10] + l2.z, trr[11] + l2.w,
                       trr[12] + l3.x};
        float best = c[0]; int bf = 0;
        #pragma unroll
        for (int f = 1; f < 13; ++f) {
          bool gt = c[f] > best;              // strict >: first index wins
          best = gt ? c[f] : best;
          bf   = gt ? f : bf;
        }
        psi[t * 16 + to] = (unsigned char)bf;
      }
    }
  }
  __syncthreads();

  // ---- phase 3: ancestor maps ----
  {
    const int sS = tid & 15, g = tid >> 4;
    if (sS < 13) {
      int cur = sS;
      const int tLo = (g == 0) ? 1 : g * 16;
      for (int t = g * 16 + 15; t >= tLo; --t)
        cur = psi[t * 16 + cur];
      Mm[g * 16 + sS] = (unsigned char)cur;
    }
  }
  __syncthreads();

  // ---- phase 4: softmax output + boundary chase ----
  if (tid == 0) {
    const float* lf = &lds_ld[255 * 16];
    float m = lf[0]; int last = 0;
    #pragma unroll
    for (int i = 1; i < 13; ++i)
      if (lf[i] > m) { m = lf[i]; last = i; }   // strict >: first index
    float ssum = 0.0f;
    #pragma unroll
    for (int i = 0; i < 13; ++i) ssum += expf(lf[i] - m);
    out[b] = 1.0f / (256.0f * ssum);            // max(softmax)/T

    int cur = last;
    bnd[15] = (unsigned char)cur;
    #pragma unroll
    for (int cc = 15; cc >= 1; --cc) {
      cur = Mm[cc * 16 + cur];
      bnd[cc - 1] = (unsigned char)cur;
    }
  }
  __syncthreads();

  // ---- phase 5: interior chases ----
  if (tid < 16) {
    int cur = bnd[tid];
    const int tHi = tid * 16 + 15;
    path[tHi] = (unsigned char)cur;
    const int tLo = (tid == 0) ? 1 : tid * 16;
    for (int t = tHi; t >= tLo; --t) {
      cur = psi[t * 16 + cur];
      path[t - 1] = (unsigned char)cur;
    }
  }
  __syncthreads();

  out[256 + (long)b * 256 + tid] = (float)path[tid];
}

// ------------------------------------------------------------------ launch --
extern "C" void kernel_launch(void* const* d_in, const int* in_sizes, int n_in,
                              void* d_out, int out_size, void* d_ws, size_t ws_size,
                              hipStream_t stream) {
  const float* X     = (const float*)d_in[0];
  const float* W     = (const float*)d_in[1];
  const float* bias  = (const float*)d_in[2];
  const float* trans = (const float*)d_in[3];
  float* out    = (float*)d_out;
  float* featsT = (float*)d_ws;   // 13*65536 floats = 3.4 MB

  feats_kernel<<<512, 256, 0, stream>>>(X, W, bias, featsT);
  viterbi_kernel<<<256, 256, 0, stream>>>(featsT, trans, out);
}